// Round 1
// baseline (153.224 us; speedup 1.0000x reference)
//
#include <hip/hip_runtime.h>

// BlockConv: out[b,n,i,f] = sum_{d=-1..1} sum_{j=i-1..i+1} blocks[d+1][i][j] * x[b,n+d,j,f]
// B=4, NB=256 blocks, BS=256 rows/block, FEAT=256. fp32.
// Memory-bound: floor ~512MB @ 6.3TB/s ~ 81us.

#define NB   256
#define BS   256
#define F4   64     // FEAT/4 float4s per row
#define RPT  4      // output rows per thread
#define TY   4      // row-groups per workgroup
#define ROWS_PER_WG (RPT * TY)   // 16
#define CHUNKS (BS / ROWS_PER_WG) // 16

__global__ __launch_bounds__(256)
void blockconv_kernel(const float* __restrict__ x,
                      const float* __restrict__ w,
                      float* __restrict__ out)
{
    const int tx = threadIdx.x;            // 0..63 : float4 feature index
    const int ty = threadIdx.y;            // 0..3  : row group
    const int wg = blockIdx.x;

    const int chunk = wg & (CHUNKS - 1);   // 16 chunks per block
    const int n     = (wg >> 4) & (NB - 1);
    const int b     = wg >> 12;

    const int i_base = chunk * ROWS_PER_WG + ty * RPT;

    const float4* __restrict__ x4   = (const float4*)x;
    float4* __restrict__       out4 = (float4*)out;

    float4 acc[RPT];
#pragma unroll
    for (int i = 0; i < RPT; ++i) acc[i] = make_float4(0.f, 0.f, 0.f, 0.f);

#pragma unroll
    for (int dd = 0; dd < 3; ++dd) {
        const int nn = n + dd - 1;
        if (nn < 0 || nn >= NB) continue;
        const float4* __restrict__ xblk = x4 + ((size_t)(b * NB + nn) * BS) * F4 + tx;
        const float*  __restrict__ wblk = w + (size_t)dd * BS * BS;
        // source rows j = i_base-1 .. i_base+RPT  (RPT+2 rows)
#pragma unroll
        for (int jj = 0; jj < RPT + 2; ++jj) {
            const int j = i_base - 1 + jj;
            if (j < 0 || j >= BS) continue;
            const float4 v = xblk[(size_t)j * F4];
            // v contributes to output rows i with |i - j| <= 1
#pragma unroll
            for (int i = 0; i < RPT; ++i) {
                // di = (i_base+i) - j = i - jj + 1  -> compile-time constant
                constexpr int ONE = 1;
                const int di_ct = i - jj + ONE;
                if (di_ct < -1 || di_ct > 1) continue;
                const float wv = wblk[(size_t)(i_base + i) * BS + j];
                acc[i].x += wv * v.x;
                acc[i].y += wv * v.y;
                acc[i].z += wv * v.z;
                acc[i].w += wv * v.w;
            }
        }
    }

    const size_t obase = ((size_t)(b * NB + n) * BS + i_base) * F4 + tx;
#pragma unroll
    for (int i = 0; i < RPT; ++i)
        out4[obase + (size_t)i * F4] = acc[i];
}

extern "C" void kernel_launch(void* const* d_in, const int* in_sizes, int n_in,
                              void* d_out, int out_size, void* d_ws, size_t ws_size,
                              hipStream_t stream) {
    const float* x = (const float*)d_in[0];     // [4, 65536, 256] f32
    const float* w = (const float*)d_in[1];     // [3, 256, 256]   f32
    float* out = (float*)d_out;                 // [4, 65536, 256] f32

    const int n_wg = 4 * NB * CHUNKS;           // 16384
    dim3 block(64, TY);
    blockconv_kernel<<<n_wg, block, 0, stream>>>(x, w, out);
}

// Round 2
// 93.358 us; speedup vs baseline: 1.6412x; 1.6412x over previous
//
#include <hip/hip_runtime.h>

// BlockConv: out[b,n,i,f] = sum_{dd=0..2} sum_{|i-j|<=1} w[dd][i][j] * x[b,n+dd-1,j,f]
// B=4, NB=256, BS=256, FEAT=256, fp32. Memory-bound; floor ~524MB @6.3TB/s ~ 83us.
// R2: RPT=8, explicit 10-deep load window (MLP), branchless boundaries,
//     SGPR weights via readfirstlane, non-temporal stores.

#define NB   256
#define BS   256
#define F4   64                      // FEAT/4
#define RPT  8                       // output rows per thread
#define TY   4
#define ROWS_PER_WG (RPT * TY)       // 32
#define CHUNKS (BS / ROWS_PER_WG)    // 8

typedef float f32x4 __attribute__((ext_vector_type(4)));

__global__ __launch_bounds__(256)
void blockconv_kernel(const float* __restrict__ x,
                      const float* __restrict__ w,
                      float* __restrict__ out)
{
    const int tx = threadIdx.x;            // 0..63 : float4 feature index
    const int ty = threadIdx.y;            // 0..3  : row group (wave-uniform)
    const int wg = blockIdx.x;

    const int chunk = wg & (CHUNKS - 1);
    const int n     = (wg >> 3) & (NB - 1);
    const int b     = wg >> 11;

    const int i_base = chunk * ROWS_PER_WG + ty * RPT;
    const int jlo    = i_base - 1;
    const int jlo_cl = jlo < 0 ? 0 : jlo;              // clamp first window row
    const bool lo_ok = (jlo >= 0);
    const bool hi_ok = (jlo + RPT + 1) < BS;           // last window row valid?

    const f32x4* __restrict__ x4 = (const f32x4*)x;
    f32x4* __restrict__ out4     = (f32x4*)out;

    f32x4 acc[RPT];
#pragma unroll
    for (int i = 0; i < RPT; ++i) acc[i] = (f32x4)(0.f);

#pragma unroll
    for (int dd = 0; dd < 3; ++dd) {
        const int nn_raw = n + dd - 1;
        const bool d_ok  = (nn_raw >= 0) & (nn_raw < NB);
        const int  nn    = nn_raw < 0 ? 0 : (nn_raw >= NB ? NB - 1 : nn_raw);

        const f32x4* __restrict__ xblk = x4 + ((size_t)(b * NB + nn) * BS) * F4 + tx;
        const float* __restrict__  wblk = w + (size_t)dd * BS * BS;

        // ---- window loads: RPT+2 independent 1KiB wave-loads, issued back-to-back
        f32x4 v[RPT + 2];
        v[0] = xblk[(size_t)jlo_cl * F4];
#pragma unroll
        for (int jj = 1; jj <= RPT; ++jj)
            v[jj] = xblk[(size_t)(jlo + jj) * F4];
        v[RPT + 1] = xblk[(size_t)(hi_ok ? jlo + RPT + 1 : jlo + RPT) * F4];
        if (!lo_ok) v[0]       = (f32x4)(0.f);
        if (!hi_ok) v[RPT + 1] = (f32x4)(0.f);

        // ---- weights: wave-uniform scalars -> SGPRs via readfirstlane
        float wv[RPT][3];
#pragma unroll
        for (int ii = 0; ii < RPT; ++ii) {
            const int irow = i_base + ii;
#pragma unroll
            for (int c = 0; c < 3; ++c) {
                int j = irow - 1 + c;
                const bool j_ok = (j >= 0) & (j < BS);
                j = j < 0 ? 0 : (j >= BS ? BS - 1 : j);
                float raw = wblk[(size_t)irow * BS + j];
                raw = (d_ok & j_ok) ? raw : 0.f;       // mask OOB block / OOB row
                const int bits = __builtin_amdgcn_readfirstlane(__float_as_int(raw));
                wv[ii][c] = __int_as_float(bits);
            }
        }

        // ---- FMAs (all indices compile-time)
#pragma unroll
        for (int ii = 0; ii < RPT; ++ii) {
#pragma unroll
            for (int c = 0; c < 3; ++c) {
                const float s  = wv[ii][c];
                const f32x4 vv = v[ii + c];
                acc[ii].x = fmaf(s, vv.x, acc[ii].x);
                acc[ii].y = fmaf(s, vv.y, acc[ii].y);
                acc[ii].z = fmaf(s, vv.z, acc[ii].z);
                acc[ii].w = fmaf(s, vv.w, acc[ii].w);
            }
        }
    }

    const size_t obase = ((size_t)(b * NB + n) * BS + i_base) * F4 + tx;
#pragma unroll
    for (int i = 0; i < RPT; ++i)
        __builtin_nontemporal_store(acc[i], &out4[obase + (size_t)i * F4]);
}

extern "C" void kernel_launch(void* const* d_in, const int* in_sizes, int n_in,
                              void* d_out, int out_size, void* d_ws, size_t ws_size,
                              hipStream_t stream) {
    const float* x = (const float*)d_in[0];     // [4, 65536, 256] f32
    const float* w = (const float*)d_in[1];     // [3, 256, 256]   f32
    float* out = (float*)d_out;                 // [4, 65536, 256] f32

    const int n_wg = 4 * NB * CHUNKS;           // 8192
    dim3 block(64, TY);
    blockconv_kernel<<<n_wg, block, 0, stream>>>(x, w, out);
}